// Round 1
// baseline (126.559 us; speedup 1.0000x reference)
//
#include <hip/hip_runtime.h>
#include <math.h>

// Problem constants (match setup_inputs exactly)
constexpr int BS = 16;
constexpr int G  = 512;
constexpr int S  = 20;
constexpr int Q  = 256;
constexpr int P  = G * S;          // 10240
constexpr float THRESHOLD = 0.01f;
constexpr float BIG = 1e10f;

// Workspace layout (floats):
// [0]        bce_sum
// [1..16]    cd1_sum[16]
// [17..32]   cnt[16] (as int)
// [33..33+BS*Q) qmin[BS*Q] (as uint bits of float)
constexpr int WS_BCE  = 0;
constexpr int WS_CD1  = 1;
constexpr int WS_CNT  = 17;
constexpr int WS_QMIN = 33;

__global__ void init_ws_kernel(float* ws) {
    int i = blockIdx.x * 256 + threadIdx.x;
    if (i < 33) ws[i] = 0.0f;                       // bce_sum, cd1_sum, cnt (int 0 == float 0 bits)
    if (i < BS * Q) ((unsigned int*)ws)[WS_QMIN + i] = __float_as_uint(BIG);
}

// One thread per (b,g) cell: BCE term + masked-cell count.
__global__ void bce_cnt_kernel(const float* __restrict__ probs,
                               const float* __restrict__ target,
                               float* __restrict__ ws) {
    int i = blockIdx.x * 256 + threadIdx.x;   // 0 .. BS*G-1  (block never spans a batch: 256 | 512)
    float p = probs[i];
    float t = target[i];
    float logp   = fmaxf(logf(p), -100.0f);
    float log1mp = fmaxf(log1pf(-p), -100.0f);
    float term = -(t * logp + (1.0f - t) * log1mp);
    int c = (p > THRESHOLD) ? 1 : 0;
    // wave(64) reduce
    for (int off = 32; off; off >>= 1) {
        term += __shfl_down(term, off);
        c    += __shfl_down(c, off);
    }
    if ((threadIdx.x & 63) == 0) {
        atomicAdd(&ws[WS_BCE], term);
        atomicAdd(&((int*)ws)[WS_CNT + i / G], c * S);
    }
}

// grid = BS * (P/Q) blocks of 256 threads.
// Block handles one batch b and one 256-point chunk of P.
__global__ void chamfer_kernel(const float* __restrict__ diff_pred,  // [BS,P,3]
                               const float* __restrict__ probs,      // [BS,G]
                               const float* __restrict__ diff_gt,    // [BS,Q,3]
                               float* __restrict__ ws) {
    constexpr int CHUNKS = P / Q;            // 40
    int b     = blockIdx.x / CHUNKS;
    int chunk = blockIdx.x % CHUNKS;
    int t     = threadIdx.x;                 // 0..255

    __shared__ float spx[256], spy[256], spz[256];
    __shared__ float sgx[256], sgy[256], sgz[256];
    __shared__ unsigned char smask[256];

    int p = chunk * 256 + t;
    const float* pp = diff_pred + ((size_t)b * P + p) * 3;
    spx[t] = pp[0]; spy[t] = pp[1]; spz[t] = pp[2];
    smask[t] = probs[b * G + p / S] > THRESHOLD ? 1 : 0;
    const float* gp = diff_gt + ((size_t)b * Q + t) * 3;
    sgx[t] = gp[0]; sgy[t] = gp[1]; sgz[t] = gp[2];
    __syncthreads();

    // Phase 1 (cd1): thread t owns pred point p; min squared-dist over all q.
    {
        float px = spx[t], py = spy[t], pz = spz[t];
        float mn = 3.4e38f;
        #pragma unroll 4
        for (int q = 0; q < Q; ++q) {
            float dx = px - sgx[q], dy = py - sgy[q], dz = pz - sgz[q];
            float d  = dx * dx + dy * dy + dz * dz;
            mn = fminf(mn, d);
        }
        float contrib = smask[t] ? sqrtf(mn) : 0.0f;
        for (int off = 32; off; off >>= 1) contrib += __shfl_down(contrib, off);
        if ((t & 63) == 0) atomicAdd(&ws[WS_CD1 + b], contrib);
    }

    // Phase 2 (cd2): thread t owns gt point q=t; min squared-dist over this
    // block's masked pred points; merge via atomicMin on uint bits (dist >= 0).
    {
        float qx = sgx[t], qy = sgy[t], qz = sgz[t];
        float mn = 3.4e38f;
        #pragma unroll 4
        for (int j = 0; j < 256; ++j) {
            float dx = qx - spx[j], dy = qy - spy[j], dz = qz - spz[j];
            float d  = dx * dx + dy * dy + dz * dz;
            d = smask[j] ? d : 3.4e38f;
            mn = fminf(mn, d);
        }
        float v = (mn > 1e37f) ? BIG : sqrtf(mn);
        atomicMin(&((unsigned int*)ws)[WS_QMIN + b * Q + t], __float_as_uint(v));
    }
}

// Single block, 256 threads.
__global__ void finalize_kernel(const float* __restrict__ ws, float* __restrict__ out) {
    __shared__ float red[256];
    int t = threadIdx.x;
    float acc = 0.0f;   // meaningful on t==0 only
    for (int b = 0; b < BS; ++b) {
        red[t] = __uint_as_float(((const unsigned int*)ws)[WS_QMIN + b * Q + t]);
        __syncthreads();
        for (int s = 128; s; s >>= 1) {
            if (t < s) red[t] += red[t + s];
            __syncthreads();
        }
        if (t == 0) {
            float cd2 = red[0] / (float)Q;
            int   c   = ((const int*)ws)[WS_CNT + b];
            float cd1 = ws[WS_CD1 + b] / fmaxf((float)c, 1.0f);
            acc += (c > 0) ? fmaxf(cd1, cd2) : 0.0f;
        }
        __syncthreads();
    }
    if (t == 0) {
        float pred_loss = ws[WS_BCE] / (float)(BS * G);
        out[0] = pred_loss + acc / (float)BS;
    }
}

extern "C" void kernel_launch(void* const* d_in, const int* in_sizes, int n_in,
                              void* d_out, int out_size, void* d_ws, size_t ws_size,
                              hipStream_t stream) {
    const float* diff_pred   = (const float*)d_in[0];
    const float* probs_pred  = (const float*)d_in[1];
    const float* diff_gt     = (const float*)d_in[2];
    const float* prob_target = (const float*)d_in[3];
    float* out = (float*)d_out;
    float* ws  = (float*)d_ws;

    init_ws_kernel<<<(BS * Q + 255) / 256, 256, 0, stream>>>(ws);
    bce_cnt_kernel<<<(BS * G) / 256, 256, 0, stream>>>(probs_pred, prob_target, ws);
    chamfer_kernel<<<BS * (P / Q), 256, 0, stream>>>(diff_pred, probs_pred, diff_gt, ws);
    finalize_kernel<<<1, 256, 0, stream>>>(ws, out);
}